// Round 2
// baseline (102.942 us; speedup 1.0000x reference)
//
#include <hip/hip_runtime.h>
#include <hip/hip_bf16.h>

// MaskedDenseLayerMultiMasks: out[b,m,o] = sum_i x[b,m,i] * kernel[i,o] * masks[m,i,o]
// bf16 MFMA GEMM, fused fp32->bf16 convert + mask-multiply during reg staging.
// Round 2: software-pipelined (loads t+1 issued before MFMA t), vectorized B loads
// with in-register 4x4 transpose, XOR-granule-swizzled Bs, LDS double-buffer,
// single barrier per K-iter, BK=64.

#define BATCH 512
#define NMASK 16
#define IN_D  1024
#define OUT_D 1024

#define BM 128
#define BN 128
#define BK 64
#define NT (IN_D / BK)   // 16
#define AKP 72           // padded A k-stride (144B rows: frag reads at bank floor)
#define THREADS 256

using bf16x8  = __attribute__((ext_vector_type(8))) __bf16;
using bf16x4t = __attribute__((ext_vector_type(4))) __bf16;
using f32x4   = __attribute__((ext_vector_type(4))) float;
using u16x8   = __attribute__((ext_vector_type(8))) unsigned short;
using u16x4   = __attribute__((ext_vector_type(4))) unsigned short;

__device__ __forceinline__ unsigned short f2bf(float f) {
    unsigned u = __float_as_uint(f);
    u += 0x7fffu + ((u >> 16) & 1u);          // RNE
    return (unsigned short)(u >> 16);
}

// bijective per-row granule swizzle for Bs[o][k]: granule = 4 bf16 (8B)
__device__ __forceinline__ int physg(int g, int o) {
    return g ^ (o & 15) ^ ((o >> 4) & 7);
}

__global__ void __launch_bounds__(THREADS, 2)
mdl_mfma_kernel(const float* __restrict__ X,   // (B, M, I)
                const float* __restrict__ Kn,  // (I, O)
                const float* __restrict__ Mk,  // (M, I, O)
                float* __restrict__ Out)       // (B, M, O)
{
    __shared__ __align__(16) unsigned short As[2][BM * AKP];
    __shared__ __align__(16) unsigned short Bs[2][BN * BK];

    const int t = threadIdx.x;
    const int l = t & 63;
    const int w = t >> 6;

    // XCD-aware bijective swizzle (512 wgs, 8 XCDs, 64/XCD): per-XCD 2 masks,
    // bb innermost for B-tile L2 reuse.
    const int raw = blockIdx.x;
    const int wg  = (raw & 7) * 64 + (raw >> 3);
    const int m   = wg >> 5;          // 0..15
    const int ob  = (wg >> 2) & 7;    // 0..7
    const int bb  = wg & 3;           // 0..3

    const int wr = w >> 1, wc = w & 1;

    f32x4 acc[4][4];
#pragma unroll
    for (int mi = 0; mi < 4; ++mi)
#pragma unroll
        for (int ni = 0; ni < 4; ++ni)
            acc[mi][ni] = (f32x4){0.f, 0.f, 0.f, 0.f};

    // A staging map: row = ld*32 + t/8, k-chunk = (t&7)*8 (32B contiguous/row-slice)
    const int a_row = t >> 3;
    const int a_k   = (t & 7) * 8;
    // B staging map: 4x4 (i,o) patches: og = t&31 -> o_l = og*4; ig = t>>5 (+8 for pi=1)
    const int og  = t & 31;
    const int o_l = og * 4;
    const int igb = t >> 5;

    const float* Mkm = Mk + (size_t)m * IN_D * OUT_D;

    // pipeline registers
    f32x4 av[4][2];
    f32x4 kv[2][4], mv[2][4];

    auto LOAD = [&](int kt) {
#pragma unroll
        for (int ld = 0; ld < 4; ++ld) {
            const int row = ld * 32 + a_row;
            const float* p = X + ((size_t)(bb * BM + row) * NMASK + m) * IN_D + kt + a_k;
            av[ld][0] = *(const f32x4*)p;
            av[ld][1] = *(const f32x4*)(p + 4);
        }
#pragma unroll
        for (int pi = 0; pi < 2; ++pi) {
            const int i_l = (igb + pi * 8) * 4;
#pragma unroll
            for (int r = 0; r < 4; ++r) {
                const size_t go = (size_t)(kt + i_l + r) * OUT_D + ob * BN + o_l;
                kv[pi][r] = *(const f32x4*)(Kn + go);
                mv[pi][r] = *(const f32x4*)(Mkm + go);
            }
        }
    };

    auto STORE = [&](int buf) {
        // A: convert 8 floats -> one b128 LDS write per ld
#pragma unroll
        for (int ld = 0; ld < 4; ++ld) {
            const int row = ld * 32 + a_row;
            u16x8 v;
#pragma unroll
            for (int j = 0; j < 4; ++j) { v[j] = f2bf(av[ld][0][j]); v[4 + j] = f2bf(av[ld][1][j]); }
            *(u16x8*)(&As[buf][row * AKP + a_k]) = v;
        }
        // B: multiply, in-register 4x4 transpose, k-contiguous b64 writes (swizzled)
#pragma unroll
        for (int pi = 0; pi < 2; ++pi) {
            const int g = igb + pi * 8;
#pragma unroll
            for (int c = 0; c < 4; ++c) {
                const int o = o_l + c;
                u16x4 v;
#pragma unroll
                for (int r = 0; r < 4; ++r) v[r] = f2bf(kv[pi][r][c] * mv[pi][r][c]);
                *(u16x4*)(&Bs[buf][o * BK + physg(g, o) * 4]) = v;
            }
        }
    };

    auto MFMA_PHASE = [&](int buf) {
#pragma unroll
        for (int s = 0; s < 2; ++s) {
            bf16x8 af[4], bfr[4];
            const int kg = s * 32 + (l >> 4) * 8;
#pragma unroll
            for (int mi = 0; mi < 4; ++mi) {
                const int r = wr * 64 + mi * 16 + (l & 15);
                af[mi] = *(const bf16x8*)(&As[buf][r * AKP + kg]);
            }
            const int Gb = s * 8 + (l >> 4) * 2;
#pragma unroll
            for (int ni = 0; ni < 4; ++ni) {
                const int n = wc * 64 + ni * 16 + (l & 15);
                bf16x4t lo = *(const bf16x4t*)(&Bs[buf][n * BK + physg(Gb, n) * 4]);
                bf16x4t hi = *(const bf16x4t*)(&Bs[buf][n * BK + physg(Gb + 1, n) * 4]);
                bf16x8 f;
                f[0] = lo[0]; f[1] = lo[1]; f[2] = lo[2]; f[3] = lo[3];
                f[4] = hi[0]; f[5] = hi[1]; f[6] = hi[2]; f[7] = hi[3];
                bfr[ni] = f;
            }
#pragma unroll
            for (int mi = 0; mi < 4; ++mi)
#pragma unroll
                for (int ni = 0; ni < 4; ++ni)
                    acc[mi][ni] = __builtin_amdgcn_mfma_f32_16x16x32_bf16(
                        af[mi], bfr[ni], acc[mi][ni], 0, 0, 0);
        }
    };

    // ---- pipelined main loop: 1 barrier per K-iter ----
    LOAD(0);
    STORE(0);
    __syncthreads();
#pragma unroll 2
    for (int tt = 0; tt < NT; ++tt) {
        const int cur = tt & 1;
        if (tt + 1 < NT) LOAD((tt + 1) * BK);   // async; consumed after MFMA
        MFMA_PHASE(cur);
        if (tt + 1 < NT) STORE(cur ^ 1);        // vmcnt wait lands here, post-MFMA
        __syncthreads();
    }

    // ---- epilogue: C/D layout col = l&15, row = (l>>4)*4 + reg ----
    const int r0 = bb * BM + wr * 64 + (l >> 4) * 4;
    const int c0 = ob * BN + wc * 64 + (l & 15);
#pragma unroll
    for (int mi = 0; mi < 4; ++mi) {
#pragma unroll
        for (int j = 0; j < 4; ++j) {
            const size_t row = (size_t)(r0 + mi * 16 + j);
            float* op = Out + (row * NMASK + m) * OUT_D + c0;
#pragma unroll
            for (int ni = 0; ni < 4; ++ni)
                op[ni * 16] = acc[mi][ni][j];
        }
    }
}

extern "C" void kernel_launch(void* const* d_in, const int* in_sizes, int n_in,
                              void* d_out, int out_size, void* d_ws, size_t ws_size,
                              hipStream_t stream) {
    (void)in_sizes; (void)n_in; (void)d_ws; (void)ws_size; (void)out_size;
    const float* X  = (const float*)d_in[0];
    const float* Kn = (const float*)d_in[1];
    const float* Mk = (const float*)d_in[2];
    float* Out = (float*)d_out;

    const int nblocks = (BATCH / BM) * (OUT_D / BN) * NMASK;  // 512
    mdl_mfma_kernel<<<nblocks, THREADS, 0, stream>>>(X, Kn, Mk, Out);
}

// Round 3
// 55.502 us; speedup vs baseline: 1.8548x; 1.8548x over previous
//
#include <hip/hip_runtime.h>
#include <hip/hip_bf16.h>

// MaskedDenseLayerMultiMasks: out[b,m,o] = sum_i x[b,m,i] * kernel[i,o] * masks[m,i,o]
// bf16 MFMA GEMM, fused fp32->bf16 convert + mask-multiply during reg staging.
// Round 3: back to round-1's no-spill ordering (LOAD; bar; STORE; bar; MFMA),
// but 512-thread blocks -> 16 waves/CU (2x TLP), half the per-thread staging
// state. 128x128 tile kept (L2-traffic-optimal for the 4x convert redundancy).

#define BATCH 512
#define NMASK 16
#define IN_D  1024
#define OUT_D 1024

#define BM 128
#define BN 128
#define BK 32
#define NT (IN_D / BK)   // 32
#define AKP 40           // A LDS k-stride (80B rows -> 2-way b128 reads, free)
#define BKP 36           // B LDS k-stride (72B rows -> ~2-way b64 reads)
#define THREADS 512

using bf16x8  = __attribute__((ext_vector_type(8))) __bf16;
using bf16x4t = __attribute__((ext_vector_type(4))) __bf16;
using f32x4   = __attribute__((ext_vector_type(4))) float;
using f32x2   = __attribute__((ext_vector_type(2))) float;
using u16x8   = __attribute__((ext_vector_type(8))) unsigned short;
using u16x4   = __attribute__((ext_vector_type(4))) unsigned short;

__device__ __forceinline__ unsigned short f2bf(float f) {
    unsigned u = __float_as_uint(f);
    u += 0x7fffu + ((u >> 16) & 1u);          // RNE
    return (unsigned short)(u >> 16);
}

__global__ void __launch_bounds__(THREADS, 4)
mdl_mfma_kernel(const float* __restrict__ X,   // (B, M, I)
                const float* __restrict__ Kn,  // (I, O)
                const float* __restrict__ Mk,  // (M, I, O)
                float* __restrict__ Out)       // (B, M, O)
{
    __shared__ __align__(16) unsigned short As[BM * AKP];  // As[row][k]
    __shared__ __align__(16) unsigned short Bs[BN * BKP];  // Bs[o][k]

    const int t = threadIdx.x;
    const int l = t & 63;
    const int w = t >> 6;          // wave 0..7

    // XCD-aware bijective swizzle: 512 wgs, 8 XCDs, 64 contiguous wgs/XCD.
    // Per XCD: 2 masks; bb innermost so B-panel-sharing blocks are co-resident.
    const int raw = blockIdx.x;
    const int wg  = (raw & 7) * 64 + (raw >> 3);
    const int m   = wg >> 5;          // 0..15
    const int ob  = (wg >> 2) & 7;    // 0..7
    const int bb  = wg & 3;           // 0..3

    // wave -> 64x32 sub-tile: 2 row-halves x 4 col-quarters
    const int wr = w >> 2;            // 0..1
    const int wc = w & 3;             // 0..3

    f32x4 acc[4][2];
#pragma unroll
    for (int mi = 0; mi < 4; ++mi)
#pragma unroll
        for (int ni = 0; ni < 2; ++ni)
            acc[mi][ni] = (f32x4){0.f, 0.f, 0.f, 0.f};

    // A staging: row = t/4 (0..127), k-chunk = (t&3)*8 -> two f32x4, one b128 write
    const int a_row = t >> 2;
    const int a_k   = (t & 3) * 8;
    // B staging: 4i x 2o patch: og = t&63 -> o_l = og*2; ig = t>>6 -> i_l = ig*4
    const int o_l = (t & 63) * 2;
    const int i_l = (t >> 6) * 4;
    const int ig  = t >> 6;

    const float* Xa  = X + ((size_t)(bb * BM + a_row) * NMASK + m) * IN_D + a_k;
    const float* Knb = Kn + (size_t)i_l * OUT_D + ob * BN + o_l;
    const float* Mkb = Mk + ((size_t)m * IN_D + i_l) * OUT_D + ob * BN + o_l;

    for (int tt = 0; tt < NT; ++tt) {
        const int kt = tt * BK;

        // ---- issue global loads (before barrier: latency overlaps wait) ----
        f32x4 av0 = *(const f32x4*)(Xa + kt);
        f32x4 av1 = *(const f32x4*)(Xa + kt + 4);
        f32x2 kv[4], mv[4];
#pragma unroll
        for (int r = 0; r < 4; ++r) {
            kv[r] = *(const f32x2*)(Knb + (size_t)(kt + r) * OUT_D);
            mv[r] = *(const f32x2*)(Mkb + (size_t)(kt + r) * OUT_D);
        }

        __syncthreads();   // prev iter's frag reads complete

        // ---- convert + LDS write ----
        {
            u16x8 v;
#pragma unroll
            for (int j = 0; j < 4; ++j) { v[j] = f2bf(av0[j]); v[4 + j] = f2bf(av1[j]); }
            *(u16x8*)(&As[a_row * AKP + a_k]) = v;
        }
#pragma unroll
        for (int c = 0; c < 2; ++c) {
            u16x4 v;
#pragma unroll
            for (int r = 0; r < 4; ++r) v[r] = f2bf(kv[r][c] * mv[r][c]);
            *(u16x4*)(&Bs[(o_l + c) * BKP + ig * 4]) = v;
        }

        __syncthreads();

        // ---- fragments + MFMA ----
        const int kg = (l >> 4) * 8;
        bf16x8 af[4], bf[2];
#pragma unroll
        for (int mi = 0; mi < 4; ++mi) {
            const int r = wr * 64 + mi * 16 + (l & 15);
            af[mi] = *(const bf16x8*)(&As[r * AKP + kg]);
        }
#pragma unroll
        for (int ni = 0; ni < 2; ++ni) {
            const int n = wc * 32 + ni * 16 + (l & 15);
            bf16x4t lo = *(const bf16x4t*)(&Bs[n * BKP + kg]);
            bf16x4t hi = *(const bf16x4t*)(&Bs[n * BKP + kg + 4]);
            bf16x8 f;
            f[0] = lo[0]; f[1] = lo[1]; f[2] = lo[2]; f[3] = lo[3];
            f[4] = hi[0]; f[5] = hi[1]; f[6] = hi[2]; f[7] = hi[3];
            bf[ni] = f;
        }
#pragma unroll
        for (int mi = 0; mi < 4; ++mi)
#pragma unroll
            for (int ni = 0; ni < 2; ++ni)
                acc[mi][ni] = __builtin_amdgcn_mfma_f32_16x16x32_bf16(
                    af[mi], bf[ni], acc[mi][ni], 0, 0, 0);
    }

    // ---- epilogue: C/D layout col = l&15, row = (l>>4)*4 + reg ----
    const int r0 = bb * BM + wr * 64 + (l >> 4) * 4;
    const int c0 = ob * BN + wc * 32 + (l & 15);
#pragma unroll
    for (int mi = 0; mi < 4; ++mi) {
#pragma unroll
        for (int j = 0; j < 4; ++j) {
            const size_t row = (size_t)(r0 + mi * 16 + j);
            float* op = Out + (row * NMASK + m) * OUT_D + c0;
#pragma unroll
            for (int ni = 0; ni < 2; ++ni)
                op[ni * 16] = acc[mi][ni][j];
        }
    }
}

extern "C" void kernel_launch(void* const* d_in, const int* in_sizes, int n_in,
                              void* d_out, int out_size, void* d_ws, size_t ws_size,
                              hipStream_t stream) {
    (void)in_sizes; (void)n_in; (void)d_ws; (void)ws_size; (void)out_size;
    const float* X  = (const float*)d_in[0];
    const float* Kn = (const float*)d_in[1];
    const float* Mk = (const float*)d_in[2];
    float* Out = (float*)d_out;

    const int nblocks = (BATCH / BM) * (OUT_D / BN) * NMASK;  // 512
    mdl_mfma_kernel<<<nblocks, THREADS, 0, stream>>>(X, Kn, Mk, Out);
}

// Round 4
// 52.339 us; speedup vs baseline: 1.9668x; 1.0604x over previous
//
#include <hip/hip_runtime.h>
#include <hip/hip_bf16.h>

// MaskedDenseLayerMultiMasks: out[b,m,o] = sum_i x[b,m,i] * kernel[i,o] * masks[m,i,o]
// bf16 MFMA GEMM, fused fp32->bf16 convert + mask-multiply during reg staging.
// Round 4: round-3 geometry (512 thr, 128x128x32, 16 waves/CU) + T3 minimum
// 2-phase pipeline: LDS double-buffer, single barrier/iter, loads for t+1
// issued before MFMA(t) so global latency hides under compute. B LDS stride
// 36->34 to kill the 8-way b64-write bank conflict.

#define BATCH 512
#define NMASK 16
#define IN_D  1024
#define OUT_D 1024

#define BM 128
#define BN 128
#define BK 32
#define NT (IN_D / BK)   // 32
#define AKP 40           // A LDS k-stride: 80B rows, b128 r/w ~conflict-free
#define BKP 34           // B LDS k-stride: 68B rows, b64 writes = 32-bank partition
#define THREADS 512

using bf16x8  = __attribute__((ext_vector_type(8))) __bf16;
using bf16x4t = __attribute__((ext_vector_type(4))) __bf16;
using f32x4   = __attribute__((ext_vector_type(4))) float;
using f32x2   = __attribute__((ext_vector_type(2))) float;
using u16x8   = __attribute__((ext_vector_type(8))) unsigned short;
using u16x4   = __attribute__((ext_vector_type(4))) unsigned short;

__device__ __forceinline__ unsigned short f2bf(float f) {
    unsigned u = __float_as_uint(f);
    u += 0x7fffu + ((u >> 16) & 1u);          // RNE
    return (unsigned short)(u >> 16);
}

__global__ void __launch_bounds__(THREADS, 4)
mdl_mfma_kernel(const float* __restrict__ X,   // (B, M, I)
                const float* __restrict__ Kn,  // (I, O)
                const float* __restrict__ Mk,  // (M, I, O)
                float* __restrict__ Out)       // (B, M, O)
{
    __shared__ __align__(16) unsigned short As[2][BM * AKP];  // 20.0 KiB
    __shared__ __align__(16) unsigned short Bs[2][BN * BKP];  // 17.0 KiB

    const int t = threadIdx.x;
    const int l = t & 63;
    const int w = t >> 6;          // wave 0..7

    // XCD-aware bijective swizzle: 512 wgs, 8 XCDs, 64 contiguous wgs/XCD.
    const int raw = blockIdx.x;
    const int wg  = (raw & 7) * 64 + (raw >> 3);
    const int m   = wg >> 5;          // 0..15
    const int ob  = (wg >> 2) & 7;    // 0..7
    const int bb  = wg & 3;           // 0..3

    // wave -> 64x32 sub-tile
    const int wr = w >> 2;            // 0..1
    const int wc = w & 3;             // 0..3

    f32x4 acc[4][2];
#pragma unroll
    for (int mi = 0; mi < 4; ++mi)
#pragma unroll
        for (int ni = 0; ni < 2; ++ni)
            acc[mi][ni] = (f32x4){0.f, 0.f, 0.f, 0.f};

    // A staging: row = t/4, k-chunk = (t&3)*8
    const int a_row = t >> 2;
    const int a_k   = (t & 3) * 8;
    // B staging: 4i x 2o patch per thread
    const int o_l = (t & 63) * 2;
    const int ig  = t >> 6;           // 0..7
    const int i_l = ig * 4;

    const float* Xa  = X + ((size_t)(bb * BM + a_row) * NMASK + m) * IN_D + a_k;
    const float* Knb = Kn + (size_t)i_l * OUT_D + ob * BN + o_l;
    const float* Mkb = Mk + ((size_t)m * IN_D + i_l) * OUT_D + ob * BN + o_l;

    // pipeline registers (single copy; consumed by STORE before next LOAD)
    f32x4 av0, av1;
    f32x2 kv[4], mv[4];

    auto LOAD = [&](int kt) {
        av0 = *(const f32x4*)(Xa + kt);
        av1 = *(const f32x4*)(Xa + kt + 4);
#pragma unroll
        for (int r = 0; r < 4; ++r) {
            kv[r] = *(const f32x2*)(Knb + (size_t)(kt + r) * OUT_D);
            mv[r] = *(const f32x2*)(Mkb + (size_t)(kt + r) * OUT_D);
        }
    };

    auto STORE = [&](int buf) {
        u16x8 va;
#pragma unroll
        for (int j = 0; j < 4; ++j) { va[j] = f2bf(av0[j]); va[4 + j] = f2bf(av1[j]); }
        *(u16x8*)(&As[buf][a_row * AKP + a_k]) = va;
#pragma unroll
        for (int c = 0; c < 2; ++c) {
            u16x4 v;
#pragma unroll
            for (int r = 0; r < 4; ++r) v[r] = f2bf(kv[r][c] * mv[r][c]);
            *(u16x4*)(&Bs[buf][(o_l + c) * BKP + ig * 4]) = v;
        }
    };

    auto MFMA_PHASE = [&](int buf) {
        const int kg = (l >> 4) * 8;
        bf16x8 af[4], bfv[2];
#pragma unroll
        for (int mi = 0; mi < 4; ++mi) {
            const int r = wr * 64 + mi * 16 + (l & 15);
            af[mi] = *(const bf16x8*)(&As[buf][r * AKP + kg]);
        }
#pragma unroll
        for (int ni = 0; ni < 2; ++ni) {
            const int n = wc * 32 + ni * 16 + (l & 15);
            bf16x4t lo = *(const bf16x4t*)(&Bs[buf][n * BKP + kg]);
            bf16x4t hi = *(const bf16x4t*)(&Bs[buf][n * BKP + kg + 4]);
            bf16x8 f;
            f[0] = lo[0]; f[1] = lo[1]; f[2] = lo[2]; f[3] = lo[3];
            f[4] = hi[0]; f[5] = hi[1]; f[6] = hi[2]; f[7] = hi[3];
            bfv[ni] = f;
        }
#pragma unroll
        for (int mi = 0; mi < 4; ++mi)
#pragma unroll
            for (int ni = 0; ni < 2; ++ni)
                acc[mi][ni] = __builtin_amdgcn_mfma_f32_16x16x32_bf16(
                    af[mi], bfv[ni], acc[mi][ni], 0, 0, 0);
    };

    // ---- pipelined main loop: 1 barrier per K-iter ----
    LOAD(0);
    STORE(0);
    __syncthreads();
    int cur = 0;
    for (int tt = 0; tt < NT; ++tt) {
        if (tt + 1 < NT) {
            LOAD((tt + 1) * BK);                   // issue; in flight during MFMA
            __builtin_amdgcn_sched_barrier(0);     // don't let loads sink past MFMA
        }
        MFMA_PHASE(cur);
        if (tt + 1 < NT) STORE(cur ^ 1);           // vmcnt wait lands here, post-MFMA
        __syncthreads();
        cur ^= 1;
    }

    // ---- epilogue: C/D layout col = l&15, row = (l>>4)*4 + reg ----
    const int r0 = bb * BM + wr * 64 + (l >> 4) * 4;
    const int c0 = ob * BN + wc * 32 + (l & 15);
#pragma unroll
    for (int mi = 0; mi < 4; ++mi) {
#pragma unroll
        for (int j = 0; j < 4; ++j) {
            const size_t row = (size_t)(r0 + mi * 16 + j);
            float* op = Out + (row * NMASK + m) * OUT_D + c0;
#pragma unroll
            for (int ni = 0; ni < 2; ++ni)
                op[ni * 16] = acc[mi][ni][j];
        }
    }
}

extern "C" void kernel_launch(void* const* d_in, const int* in_sizes, int n_in,
                              void* d_out, int out_size, void* d_ws, size_t ws_size,
                              hipStream_t stream) {
    (void)in_sizes; (void)n_in; (void)d_ws; (void)ws_size; (void)out_size;
    const float* X  = (const float*)d_in[0];
    const float* Kn = (const float*)d_in[1];
    const float* Mk = (const float*)d_in[2];
    float* Out = (float*)d_out;

    const int nblocks = (BATCH / BM) * (OUT_D / BN) * NMASK;  // 512
    mdl_mfma_kernel<<<nblocks, THREADS, 0, stream>>>(X, Kn, Mk, Out);
}